// Round 1
// baseline (4579.327 us; speedup 1.0000x reference)
//
#include <hip/hip_runtime.h>
#include <hip/hip_bf16.h>

#define BB 32
#define NN 256
#define HH 768
#define NHEADS 12
#define DH 64
#define PHDIM 128
#define NVOCAB 35

// ---------------------------------------------------------------------------
// Kernel 1: LN(pos_table) @ Wsk/Wsv -> 35x64 vocab tables
// grid = 35 blocks, 128 threads
// ---------------------------------------------------------------------------
__global__ void k_vocab(const float* __restrict__ pos_table,
                        const float* __restrict__ g_path, const float* __restrict__ b_path,
                        const float* __restrict__ Wsk, const float* __restrict__ bsk,
                        const float* __restrict__ Wsv, const float* __restrict__ bsv,
                        float* __restrict__ skv, float* __restrict__ svv) {
    __shared__ float x[PHDIM];
    __shared__ float red[PHDIM];
    int v = blockIdx.x;
    int t = threadIdx.x;  // 128
    float xv = pos_table[v * PHDIM + t];
    red[t] = xv;
    __syncthreads();
    for (int s = 64; s > 0; s >>= 1) { if (t < s) red[t] += red[t + s]; __syncthreads(); }
    float mean = red[0] / PHDIM;
    __syncthreads();
    float c = xv - mean;
    red[t] = c * c;
    __syncthreads();
    for (int s = 64; s > 0; s >>= 1) { if (t < s) red[t] += red[t + s]; __syncthreads(); }
    float var = red[0] / PHDIM;
    float ln = (xv - mean) * rsqrtf(var + 1e-5f) * g_path[t] + b_path[t];
    __syncthreads();
    x[t] = ln;
    __syncthreads();
    if (t < 64) {
        float acc = bsk[t];
        for (int p = 0; p < PHDIM; ++p) acc += x[p] * Wsk[p * DH + t];
        skv[v * DH + t] = acc;
    } else {
        int d = t - 64;
        float acc = bsv[d];
        for (int p = 0; p < PHDIM; ++p) acc += x[p] * Wsv[p * DH + d];
        svv[v * DH + d] = acc;
    }
}

// ---------------------------------------------------------------------------
// Kernel 2: QKV projection GEMM  (8192x768) @ (768x2304), f32 tiled 64x64x16
// grid = (128, 36), 256 threads, 4x4 per thread.
// Epilogue scatters into per-head (B,HEADS,N,DH) layout; q scaled by 1/8.
// ---------------------------------------------------------------------------
__global__ __launch_bounds__(256) void k_qkv(
        const float* __restrict__ A,
        const float* __restrict__ Wq, const float* __restrict__ bq,
        const float* __restrict__ Wk, const float* __restrict__ bk,
        const float* __restrict__ Wv, const float* __restrict__ bv,
        float* __restrict__ qo, float* __restrict__ ko, float* __restrict__ vo) {
    __shared__ float As[16][65];   // As[kk][row]
    __shared__ float Bs[16][65];   // Bs[kk][col]
    int bm = blockIdx.x;
    int bn = blockIdx.y;
    int tid = threadIdx.x;
    int colBase = bn * 64;
    int sel = colBase / HH;                 // 0=q,1=k,2=v (tiles never straddle)
    int jjBase = colBase - sel * HH;
    const float* W    = (sel == 0) ? Wq : ((sel == 1) ? Wk : Wv);
    const float* bias = (sel == 0) ? bq : ((sel == 1) ? bk : bv);
    float* out        = (sel == 0) ? qo : ((sel == 1) ? ko : vo);
    int ty = tid >> 4, tx = tid & 15;
    int rowBase = bm * 64;
    float acc[4][4] = {};
    for (int k0 = 0; k0 < HH; k0 += 16) {
#pragma unroll
        for (int l = 0; l < 4; ++l) {
            int e = tid + l * 256;
            int r = e >> 4, kk = e & 15;
            As[kk][r] = A[(size_t)(rowBase + r) * HH + k0 + kk];
        }
#pragma unroll
        for (int l = 0; l < 4; ++l) {
            int e = tid + l * 256;
            int kk = e >> 6, cc = e & 63;
            Bs[kk][cc] = W[(size_t)(k0 + kk) * HH + jjBase + cc];
        }
        __syncthreads();
#pragma unroll
        for (int kk = 0; kk < 16; ++kk) {
            float a[4], bb[4];
#pragma unroll
            for (int i = 0; i < 4; ++i) a[i] = As[kk][ty * 4 + i];
#pragma unroll
            for (int j = 0; j < 4; ++j) bb[j] = Bs[kk][tx * 4 + j];
#pragma unroll
            for (int i = 0; i < 4; ++i)
#pragma unroll
                for (int j = 0; j < 4; ++j) acc[i][j] += a[i] * bb[j];
        }
        __syncthreads();
    }
#pragma unroll
    for (int i = 0; i < 4; ++i) {
        int row = rowBase + ty * 4 + i;
        int b = row >> 8, ii = row & 255;
#pragma unroll
        for (int j = 0; j < 4; ++j) {
            int jj = jjBase + tx * 4 + j;
            int h = jj >> 6, d = jj & 63;
            float val = acc[i][j] + bias[jj];
            if (sel == 0) val *= 0.125f;   // DH^-0.5
            out[((size_t)(b * NHEADS + h) * NN + ii) * DH + d] = val;
        }
    }
}

// ---------------------------------------------------------------------------
// Kernel 3: attention per (b,h) x 16-row q tile.
// S = q k^T + qs[pool] + bias -> softmax -> w (written to output 2)
// out = w @ v + (hist_vocab(w) @ svv)     -> attn_out (B,N,H)
// grid = (384, 16), 256 threads. ~61 KB LDS -> 1 block/CU.
// ---------------------------------------------------------------------------
__global__ __launch_bounds__(256) void k_attn(
        const float* __restrict__ q, const float* __restrict__ k,
        const float* __restrict__ v,
        const float* __restrict__ skv, const float* __restrict__ svv,
        const int* __restrict__ pool, const float* __restrict__ bias,
        float* __restrict__ wout, float* __restrict__ attn_out) {
    __shared__ float q_s[16][DH];
    __shared__ float S_s[16][NN];
    __shared__ float kv_s[64][DH];
    __shared__ float skv_s[NVOCAB][DH];
    __shared__ float svv_s[NVOCAB][DH];
    __shared__ float qs_s[16][NVOCAB];
    __shared__ float wsum_s[16][NVOCAB];
    __shared__ float bias_s[NN];
    __shared__ float red_s[16][17];

    int bh = blockIdx.x;
    int it = blockIdx.y;
    int b = bh / NHEADS;
    int h = bh - b * NHEADS;
    int r0 = it * 16;
    int tid = threadIdx.x;

#pragma unroll
    for (int l = 0; l < 4; ++l) {
        int e = tid + l * 256;
        int r = e >> 6, d = e & 63;
        q_s[r][d] = q[((size_t)bh * NN + r0 + r) * DH + d];
    }
    for (int e = tid; e < NVOCAB * DH; e += 256) {
        skv_s[e / DH][e % DH] = skv[e];
        svv_s[e / DH][e % DH] = svv[e];
    }
    if (tid < NN) bias_s[tid] = bias[b * NN + tid];
    __syncthreads();

    // qs[r][vocab] = q_row . skv[vocab]
    for (int e = tid; e < 16 * NVOCAB; e += 256) {
        int r = e / NVOCAB, vc = e % NVOCAB;
        float acc = 0.f;
        for (int d = 0; d < DH; ++d) acc += q_s[r][d] * skv_s[vc][d];
        qs_s[r][vc] = acc;
    }
    __syncthreads();

    // S
    for (int jt = 0; jt < 4; ++jt) {
#pragma unroll
        for (int l = 0; l < 16; ++l) {
            int e = tid + l * 256;
            int jj = e >> 6, d = e & 63;
            kv_s[jj][d] = k[((size_t)bh * NN + jt * 64 + jj) * DH + d];
        }
        __syncthreads();
#pragma unroll
        for (int l = 0; l < 4; ++l) {
            int e = tid + l * 256;
            int r = e >> 6, jj = e & 63;
            int jg = jt * 64 + jj;
            float acc = 0.f;
            for (int d = 0; d < DH; ++d) acc += q_s[r][d] * kv_s[jj][d];
            int pv = pool[(size_t)(r0 + r) * NN + jg];
            S_s[r][jg] = acc + qs_s[r][pv] + bias_s[jg];
        }
        __syncthreads();
    }

    // softmax: 16 threads per row
    {
        int r = tid >> 4, t = tid & 15;
        float m = -1e30f;
        for (int jj = t; jj < NN; jj += 16) m = fmaxf(m, S_s[r][jj]);
        red_s[r][t] = m;
        __syncthreads();
        if (t == 0) {
            float mm = red_s[r][0];
            for (int s = 1; s < 16; ++s) mm = fmaxf(mm, red_s[r][s]);
            red_s[r][16] = mm;
        }
        __syncthreads();
        float mm = red_s[r][16];
        float sum = 0.f;
        for (int jj = t; jj < NN; jj += 16) {
            float e = __expf(S_s[r][jj] - mm);
            S_s[r][jj] = e;
            sum += e;
        }
        red_s[r][t] = sum;
        __syncthreads();
        if (t == 0) {
            float ss = 0.f;
            for (int s = 0; s < 16; ++s) ss += red_s[r][s];
            red_s[r][16] = 1.0f / ss;
        }
        __syncthreads();
        float inv = red_s[r][16];
        for (int jj = t; jj < NN; jj += 16) S_s[r][jj] *= inv;
    }
    __syncthreads();

    // write w
#pragma unroll
    for (int l = 0; l < 16; ++l) {
        int e = tid + l * 256;
        int r = e >> 8, jj = e & 255;
        wout[((size_t)bh * NN + r0 + r) * NN + jj] = S_s[r][jj];
    }

    // vocab histogram of w
    for (int e = tid; e < 16 * NVOCAB; e += 256) wsum_s[e / NVOCAB][e % NVOCAB] = 0.f;
    __syncthreads();
    {
        int r = tid >> 4, t = tid & 15;
        for (int jj = t; jj < NN; jj += 16) {
            int pv = pool[(size_t)(r0 + r) * NN + jj];
            atomicAdd(&wsum_s[r][pv], S_s[r][jj]);
        }
    }
    __syncthreads();

    // out = w@v  (tiled over j) then += wsum@svv
    float acc[4] = {0.f, 0.f, 0.f, 0.f};
    for (int jt = 0; jt < 4; ++jt) {
        __syncthreads();
#pragma unroll
        for (int l = 0; l < 16; ++l) {
            int e = tid + l * 256;
            int jj = e >> 6, d = e & 63;
            kv_s[jj][d] = v[((size_t)bh * NN + jt * 64 + jj) * DH + d];
        }
        __syncthreads();
#pragma unroll
        for (int p = 0; p < 4; ++p) {
            int e = tid + p * 256;
            int r = e >> 6, d = e & 63;
            float a = 0.f;
            for (int jj = 0; jj < 64; ++jj) a += S_s[r][jt * 64 + jj] * kv_s[jj][d];
            acc[p] += a;
        }
    }
#pragma unroll
    for (int p = 0; p < 4; ++p) {
        int e = tid + p * 256;
        int r = e >> 6, d = e & 63;
        float a = acc[p];
        for (int vc = 0; vc < NVOCAB; ++vc) a += wsum_s[r][vc] * svv_s[vc][d];
        attn_out[((size_t)(b * NN + r0 + r)) * HH + h * DH + d] = a;
    }
}

// ---------------------------------------------------------------------------
// Kernel 4: O projection GEMM (8192x768)@(768x768) + bias + relu
// ---------------------------------------------------------------------------
__global__ __launch_bounds__(256) void k_ogemm(
        const float* __restrict__ A, const float* __restrict__ W,
        const float* __restrict__ bo, float* __restrict__ Cout) {
    __shared__ float As[16][65];
    __shared__ float Bs[16][65];
    int bm = blockIdx.x;
    int bn = blockIdx.y;
    int tid = threadIdx.x;
    int colBase = bn * 64;
    int ty = tid >> 4, tx = tid & 15;
    int rowBase = bm * 64;
    float acc[4][4] = {};
    for (int k0 = 0; k0 < HH; k0 += 16) {
#pragma unroll
        for (int l = 0; l < 4; ++l) {
            int e = tid + l * 256;
            int r = e >> 4, kk = e & 15;
            As[kk][r] = A[(size_t)(rowBase + r) * HH + k0 + kk];
        }
#pragma unroll
        for (int l = 0; l < 4; ++l) {
            int e = tid + l * 256;
            int kk = e >> 6, cc = e & 63;
            Bs[kk][cc] = W[(size_t)(k0 + kk) * HH + colBase + cc];
        }
        __syncthreads();
#pragma unroll
        for (int kk = 0; kk < 16; ++kk) {
            float a[4], bb[4];
#pragma unroll
            for (int i = 0; i < 4; ++i) a[i] = As[kk][ty * 4 + i];
#pragma unroll
            for (int j = 0; j < 4; ++j) bb[j] = Bs[kk][tx * 4 + j];
#pragma unroll
            for (int i = 0; i < 4; ++i)
#pragma unroll
                for (int j = 0; j < 4; ++j) acc[i][j] += a[i] * bb[j];
        }
        __syncthreads();
    }
#pragma unroll
    for (int i = 0; i < 4; ++i) {
        int row = rowBase + ty * 4 + i;
#pragma unroll
        for (int j = 0; j < 4; ++j) {
            int col = colBase + tx * 4 + j;
            float val = acc[i][j] + bo[col];
            Cout[(size_t)row * HH + col] = fmaxf(val, 0.f);
        }
    }
}

// ---------------------------------------------------------------------------
// Kernel 5: final LayerNorm(nodes + proj)
// grid = 8192 rows, 256 threads, 3 elems/thread
// ---------------------------------------------------------------------------
__global__ __launch_bounds__(256) void k_ln(
        const float* __restrict__ nodes, const float* __restrict__ proj,
        const float* __restrict__ g, const float* __restrict__ bta,
        float* __restrict__ out) {
    __shared__ float red[256];
    int row = blockIdx.x;
    int tid = threadIdx.x;
    float x[3];
    float s = 0.f;
#pragma unroll
    for (int l = 0; l < 3; ++l) {
        int c = tid + l * 256;
        x[l] = nodes[(size_t)row * HH + c] + proj[(size_t)row * HH + c];
        s += x[l];
    }
    red[tid] = s;
    __syncthreads();
    for (int st = 128; st > 0; st >>= 1) { if (tid < st) red[tid] += red[tid + st]; __syncthreads(); }
    float mean = red[0] / HH;
    __syncthreads();
    float vs = 0.f;
#pragma unroll
    for (int l = 0; l < 3; ++l) { float c = x[l] - mean; vs += c * c; }
    red[tid] = vs;
    __syncthreads();
    for (int st = 128; st > 0; st >>= 1) { if (tid < st) red[tid] += red[tid + st]; __syncthreads(); }
    float inv = rsqrtf(red[0] / HH + 1e-5f);
#pragma unroll
    for (int l = 0; l < 3; ++l) {
        int c = tid + l * 256;
        out[(size_t)row * HH + c] = (x[l] - mean) * inv * g[c] + bta[c];
    }
}

// ---------------------------------------------------------------------------
extern "C" void kernel_launch(void* const* d_in, const int* in_sizes, int n_in,
                              void* d_out, int out_size, void* d_ws, size_t ws_size,
                              hipStream_t stream) {
    const float* nodes     = (const float*)d_in[0];
    const float* bias      = (const float*)d_in[1];
    const int*   pool      = (const int*)d_in[2];
    const float* pos_table = (const float*)d_in[3];
    const float* Wq = (const float*)d_in[4];  const float* bq = (const float*)d_in[5];
    const float* Wk = (const float*)d_in[6];  const float* bk = (const float*)d_in[7];
    const float* Wv = (const float*)d_in[8];  const float* bv = (const float*)d_in[9];
    const float* Wsk = (const float*)d_in[10]; const float* bsk = (const float*)d_in[11];
    const float* Wsv = (const float*)d_in[12]; const float* bsv = (const float*)d_in[13];
    const float* Wo = (const float*)d_in[14]; const float* bo = (const float*)d_in[15];
    const float* g_path = (const float*)d_in[16]; const float* b_path = (const float*)d_in[17];
    const float* g_norm = (const float*)d_in[18]; const float* b_norm = (const float*)d_in[19];

    float* out0 = (float*)d_out;                         // (B,N,H)
    float* wout = out0 + (size_t)BB * NN * HH;           // (B,HEADS,N,N)

    float* ws = (float*)d_ws;
    size_t per = (size_t)BB * NHEADS * NN * DH;          // 6,291,456
    float* q_ws  = ws;
    float* k_ws  = q_ws + per;
    float* v_ws  = k_ws + per;
    float* ao_ws = v_ws + per;
    float* skv   = ao_ws + per;
    float* svv   = skv + NVOCAB * DH;
    // O-projection output reuses q_ws (q is dead by then)

    k_vocab<<<NVOCAB, 128, 0, stream>>>(pos_table, g_path, b_path, Wsk, bsk, Wsv, bsv, skv, svv);

    dim3 g2(128, 36);
    k_qkv<<<g2, 256, 0, stream>>>(nodes, Wq, bq, Wk, bk, Wv, bv, q_ws, k_ws, v_ws);

    dim3 g3(BB * NHEADS, 16);
    k_attn<<<g3, 256, 0, stream>>>(q_ws, k_ws, v_ws, skv, svv, pool, bias, wout, ao_ws);

    dim3 g4(128, 12);
    k_ogemm<<<g4, 256, 0, stream>>>(ao_ws, Wo, bo, q_ws);

    k_ln<<<BB * NN, 256, 0, stream>>>(nodes, q_ws, g_norm, b_norm, out0);
}

// Round 2
// 892.431 us; speedup vs baseline: 5.1313x; 5.1313x over previous
//
#include <hip/hip_runtime.h>
#include <hip/hip_bf16.h>

#define BB 32
#define NN 256
#define HH 768
#define NHEADS 12
#define DH 64
#define PHDIM 128
#define NVOCAB 35

typedef short bf16x8 __attribute__((ext_vector_type(8)));
typedef float f32x16 __attribute__((ext_vector_type(16)));

#define MFMA32 __builtin_amdgcn_mfma_f32_32x32x16_bf16

// round-to-nearest-even f32 -> bf16 bits
__device__ inline unsigned short f2bf(float f) {
    unsigned u = __float_as_uint(f);
    unsigned r = (u + 0x7fffu + ((u >> 16) & 1u)) >> 16;
    return (unsigned short)r;
}

__device__ inline bf16x8 pack8(const float f[8]) {
    bf16x8 r;
#pragma unroll
    for (int e = 0; e < 8; ++e) r[e] = (short)f2bf(f[e]);
    return r;
}

// ---------------------------------------------------------------------------
// Kernel 1: LN(pos_table) @ Wsk/Wsv -> bf16 vocab tables
//   skv_bf  [64][64]  (rows >=35 zero)        -- B-frag source for qs MFMA
//   svv_t_bf[64][48]  (svv transposed, cols >=35 zero) -- B-frag for struct-PV
// grid = 64 blocks, 128 threads
// ---------------------------------------------------------------------------
__global__ void k_vocab(const float* __restrict__ pos_table,
                        const float* __restrict__ g_path, const float* __restrict__ b_path,
                        const float* __restrict__ Wsk, const float* __restrict__ bsk,
                        const float* __restrict__ Wsv, const float* __restrict__ bsv,
                        unsigned short* __restrict__ skv_bf, unsigned short* __restrict__ svv_t_bf) {
    int v = blockIdx.x;
    int t = threadIdx.x;  // 128
    if (v >= NVOCAB) {    // zero padding rows/cols
        if (t < 64) skv_bf[v * 64 + t] = 0;
        else if (v < 48) svv_t_bf[(t - 64) * 48 + v] = 0;
        return;
    }
    __shared__ float x[PHDIM];
    __shared__ float red[PHDIM];
    float xv = pos_table[v * PHDIM + t];
    red[t] = xv;
    __syncthreads();
    for (int s = 64; s > 0; s >>= 1) { if (t < s) red[t] += red[t + s]; __syncthreads(); }
    float mean = red[0] / PHDIM;
    __syncthreads();
    float c = xv - mean;
    red[t] = c * c;
    __syncthreads();
    for (int s = 64; s > 0; s >>= 1) { if (t < s) red[t] += red[t + s]; __syncthreads(); }
    float var = red[0] / PHDIM;
    float ln = (xv - mean) * rsqrtf(var + 1e-5f) * g_path[t] + b_path[t];
    __syncthreads();
    x[t] = ln;
    __syncthreads();
    if (t < 64) {
        float acc = bsk[t];
        for (int p = 0; p < PHDIM; ++p) acc += x[p] * Wsk[p * DH + t];
        skv_bf[v * 64 + t] = f2bf(acc);
    } else {
        int d = t - 64;
        float acc = bsv[d];
        for (int p = 0; p < PHDIM; ++p) acc += x[p] * Wsv[p * DH + d];
        svv_t_bf[d * 48 + v] = f2bf(acc);
    }
}

// ---------------------------------------------------------------------------
// Kernel 2: QKV projection GEMM (8192x768)@(768x2304), f32 tiled 64x64x16.
// Epilogue writes bf16: q/k as [bh][n][64] (q scaled 1/8), v TRANSPOSED [bh][64][256].
// ---------------------------------------------------------------------------
__global__ __launch_bounds__(256) void k_qkv(
        const float* __restrict__ A,
        const float* __restrict__ Wq, const float* __restrict__ bq,
        const float* __restrict__ Wk, const float* __restrict__ bk,
        const float* __restrict__ Wv, const float* __restrict__ bv,
        unsigned short* __restrict__ q_bf, unsigned short* __restrict__ k_bf,
        unsigned short* __restrict__ v_bf_t) {
    __shared__ float As[16][65];
    __shared__ float Bs[16][65];
    __shared__ unsigned short vstage[64][66];
    int bm = blockIdx.x;
    int bn = blockIdx.y;
    int tid = threadIdx.x;
    int colBase = bn * 64;
    int sel = colBase / HH;                 // 0=q,1=k,2=v
    int jjBase = colBase - sel * HH;
    const float* W    = (sel == 0) ? Wq : ((sel == 1) ? Wk : Wv);
    const float* bias = (sel == 0) ? bq : ((sel == 1) ? bk : bv);
    int ty = tid >> 4, tx = tid & 15;
    int rowBase = bm * 64;
    float acc[4][4] = {};
    for (int k0 = 0; k0 < HH; k0 += 16) {
#pragma unroll
        for (int l = 0; l < 4; ++l) {
            int e = tid + l * 256;
            int r = e >> 4, kk = e & 15;
            As[kk][r] = A[(size_t)(rowBase + r) * HH + k0 + kk];
        }
#pragma unroll
        for (int l = 0; l < 4; ++l) {
            int e = tid + l * 256;
            int kk = e >> 6, cc = e & 63;
            Bs[kk][cc] = W[(size_t)(k0 + kk) * HH + jjBase + cc];
        }
        __syncthreads();
#pragma unroll
        for (int kk = 0; kk < 16; ++kk) {
            float a[4], bb[4];
#pragma unroll
            for (int i = 0; i < 4; ++i) a[i] = As[kk][ty * 4 + i];
#pragma unroll
            for (int j = 0; j < 4; ++j) bb[j] = Bs[kk][tx * 4 + j];
#pragma unroll
            for (int i = 0; i < 4; ++i)
#pragma unroll
                for (int j = 0; j < 4; ++j) acc[i][j] += a[i] * bb[j];
        }
        __syncthreads();
    }

    int hq = jjBase >> 6;          // head (tiles are 64-aligned -> single head, d0=tx*4)
    if (sel == 2) {
        // transpose via LDS, write v_bf_t[bh][d][n]
        __syncthreads();
#pragma unroll
        for (int i = 0; i < 4; ++i)
#pragma unroll
            for (int j = 0; j < 4; ++j)
                vstage[tx * 4 + j][ty * 4 + i] = f2bf(acc[i][j] + bias[jjBase + tx * 4 + j]);
        __syncthreads();
        int b = rowBase >> 8, n0 = rowBase & 255;
        size_t rowb = (size_t)(b * NHEADS + hq) * 64;
#pragma unroll
        for (int pass = 0; pass < 8; ++pass) {
            int d = pass * 8 + (tid >> 5);
            int c2 = tid & 31;
            unsigned val = (unsigned)vstage[d][c2 * 2] | ((unsigned)vstage[d][c2 * 2 + 1] << 16);
            *(unsigned*)&v_bf_t[(rowb + d) * 256 + n0 + c2 * 2] = val;
        }
    } else {
        unsigned short* out = (sel == 0) ? q_bf : k_bf;
        float scale = (sel == 0) ? 0.125f : 1.0f;
        int d0 = (jjBase & 63) + tx * 4;
#pragma unroll
        for (int i = 0; i < 4; ++i) {
            int row = rowBase + ty * 4 + i;
            int b = row >> 8, n = row & 255;
            ushort4 pk;
            pk.x = f2bf((acc[i][0] + bias[jjBase + tx * 4 + 0]) * scale);
            pk.y = f2bf((acc[i][1] + bias[jjBase + tx * 4 + 1]) * scale);
            pk.z = f2bf((acc[i][2] + bias[jjBase + tx * 4 + 2]) * scale);
            pk.w = f2bf((acc[i][3] + bias[jjBase + tx * 4 + 3]) * scale);
            *(ushort4*)&out[((size_t)(b * NHEADS + hq) * NN + n) * 64 + d0] = pk;
        }
    }
}

// ---------------------------------------------------------------------------
// Kernel 3: MFMA attention. grid = 768 (bh x 2 halves), 256 threads = 4 waves.
// Each wave owns 32 q-rows. Swapped QK^T (S^T = K x Q) so each lane owns one
// q-row -> register softmax. struct_w via qs lookup (pool = clip(j-i,-17,17)+17),
// struct_v via per-row vocab histogram + 3 MFMAs.
// ---------------------------------------------------------------------------
__global__ __launch_bounds__(256, 2) void k_attn(
        const unsigned short* __restrict__ q_bf, const unsigned short* __restrict__ k_bf,
        const unsigned short* __restrict__ v_bf_t,
        const unsigned short* __restrict__ skv_bf, const unsigned short* __restrict__ svv_t_bf,
        const float* __restrict__ bias,
        float* __restrict__ wout, float* __restrict__ attn_out) {
    __shared__ float qs_ws[4][32][52];   // qs then wsum (stride 52: f4-aligned rows)
    __shared__ float P_s[4][32][33];     // [w][j_off][i] staging for w-write + PV A-frags
    __shared__ float bias_s[NN];

    const int bx = blockIdx.x;
    const int bh = bx >> 1, half = bx & 1;
    const int b = bh / NHEADS, h = bh - b * NHEADS;
    const int tid = threadIdx.x;
    const int w = tid >> 6, lane = tid & 63;
    const int il = lane & 31, hi = lane >> 5;
    const int i0 = half * 128 + w * 32;
    const int ig = i0 + il;                       // this lane's q-row (global)

    bias_s[tid] = bias[b * NN + tid];

    // Q fragments: serve as B-operand (QK^T) and A-operand (qs) simultaneously
    bf16x8 qf[4];
#pragma unroll
    for (int kt = 0; kt < 4; ++kt)
        qf[kt] = *reinterpret_cast<const bf16x8*>(
            &q_bf[((size_t)(bh * NN + ig)) * 64 + kt * 16 + 8 * hi]);

    // qs = Q @ skv^T  (i x vocab), 2 col-tiles
    {
        f32x16 qa0 = {}, qa1 = {};
#pragma unroll
        for (int kt = 0; kt < 4; ++kt) {
            bf16x8 s0 = *reinterpret_cast<const bf16x8*>(&skv_bf[(size_t)il * 64 + kt * 16 + 8 * hi]);
            bf16x8 s1 = *reinterpret_cast<const bf16x8*>(&skv_bf[(size_t)(32 + il) * 64 + kt * 16 + 8 * hi]);
            qa0 = MFMA32(qf[kt], s0, qa0, 0, 0, 0);
            qa1 = MFMA32(qf[kt], s1, qa1, 0, 0, 0);
        }
#pragma unroll
        for (int r = 0; r < 16; ++r) {
            int ir = (r & 3) + 8 * (r >> 2) + 4 * hi;
            qs_ws[w][ir][il] = qa0[r];
            if (il < 3) qs_ws[w][ir][32 + il] = qa1[r];
        }
    }
    __syncthreads();

    // QK^T: S^T tiles (j x i), 8 j-tiles of 32
    f32x16 S[8] = {};
#pragma unroll
    for (int jt = 0; jt < 8; ++jt) {
#pragma unroll
        for (int kt = 0; kt < 4; ++kt) {
            bf16x8 kf = *reinterpret_cast<const bf16x8*>(
                &k_bf[((size_t)(bh * NN + jt * 32 + il)) * 64 + kt * 16 + 8 * hi]);
            S[jt] = MFMA32(kf, qf[kt], S[jt], 0, 0, 0);
        }
    }

    // add struct_w (clamped qs lookup) + bias
    {
        float qlo = qs_ws[w][il][0], qhi = qs_ws[w][il][34];
#pragma unroll
        for (int jt = 0; jt < 8; ++jt) {
#pragma unroll
            for (int rg = 0; rg < 4; ++rg) {
                int j0 = jt * 32 + rg * 8 + 4 * hi;
                float4 bv = *reinterpret_cast<const float4*>(&bias_s[j0]);
                float bvf[4] = {bv.x, bv.y, bv.z, bv.w};
#pragma unroll
                for (int e = 0; e < 4; ++e) {
                    int dd = j0 + e - ig;
                    float sw = (dd < -16) ? qlo : (dd > 16) ? qhi : qs_ws[w][il][dd + 17];
                    S[jt][rg * 4 + e] += bvf[e] + sw;
                }
            }
        }
    }

    // softmax over the lane's row (128 regs here + 128 in lane^32)
    float m = -3.4e38f;
#pragma unroll
    for (int jt = 0; jt < 8; ++jt)
#pragma unroll
        for (int r = 0; r < 16; ++r) m = fmaxf(m, S[jt][r]);
    m = fmaxf(m, __shfl_xor(m, 32));
    float sum = 0.f;
#pragma unroll
    for (int jt = 0; jt < 8; ++jt)
#pragma unroll
        for (int r = 0; r < 16; ++r) { float p = __expf(S[jt][r] - m); S[jt][r] = p; sum += p; }
    sum += __shfl_xor(sum, 32);
    float inv = 1.0f / sum;
#pragma unroll
    for (int jt = 0; jt < 8; ++jt)
#pragma unroll
        for (int r = 0; r < 16; ++r) S[jt][r] *= inv;

    // wsum histogram into qs_ws (qs is dead). zero own slice first.
#pragma unroll
    for (int c = 0; c < 26; ++c) qs_ws[w][il][hi * 26 + c] = 0.f;
    {
        float elo = 0.f, ehi = 0.f;
#pragma unroll
        for (int jt = 0; jt < 8; ++jt)
#pragma unroll
            for (int r = 0; r < 16; ++r) {
                int j = jt * 32 + (r & 3) + 8 * (r >> 2) + 4 * hi;
                int dd = j - ig;
                float p = S[jt][r];
                if (dd < -16) elo += p;
                else if (dd > 16) ehi += p;
                else qs_ws[w][il][dd + 17] = p;   // unique (i,v) slot
            }
        atomicAdd(&qs_ws[w][il][0], elo);
        atomicAdd(&qs_ws[w][il][34], ehi);
    }
    __syncthreads();

    // struct-PV: O = wsum @ svv  (k = vocab padded to 48)
    f32x16 O0 = {}, O1 = {};
#pragma unroll
    for (int kt = 0; kt < 3; ++kt) {
        float a[8];
        float4 a0 = *reinterpret_cast<const float4*>(&qs_ws[w][il][kt * 16 + 8 * hi]);
        float4 a1 = *reinterpret_cast<const float4*>(&qs_ws[w][il][kt * 16 + 8 * hi + 4]);
        a[0] = a0.x; a[1] = a0.y; a[2] = a0.z; a[3] = a0.w;
        a[4] = a1.x; a[5] = a1.y; a[6] = a1.z; a[7] = a1.w;
        bf16x8 af = pack8(a);
        bf16x8 b0 = *reinterpret_cast<const bf16x8*>(&svv_t_bf[(size_t)il * 48 + kt * 16 + 8 * hi]);
        bf16x8 b1 = *reinterpret_cast<const bf16x8*>(&svv_t_bf[(size_t)(32 + il) * 48 + kt * 16 + 8 * hi]);
        O0 = MFMA32(af, b0, O0, 0, 0, 0);
        O1 = MFMA32(af, b1, O1, 0, 0, 0);
    }

    // main PV + w output, per j-tile
#pragma unroll
    for (int jt = 0; jt < 8; ++jt) {
        // stage P^T tile: P_s[j_off][i]
#pragma unroll
        for (int r = 0; r < 16; ++r) {
            int joff = (r & 3) + 8 * (r >> 2) + 4 * hi;
            P_s[w][joff][il] = S[jt][r];
        }
        __syncthreads();
        // write w rows (coalesced)
#pragma unroll
        for (int rr = 0; rr < 16; ++rr) {
            int row = rr * 2 + hi;
            wout[((size_t)(bh * NN + i0 + row)) * NN + jt * 32 + il] = P_s[w][il < 32 ? il : 0][0] * 0.f + P_s[w][il][row];
        }
        // PV MFMAs
#pragma unroll
        for (int kt = 0; kt < 2; ++kt) {
            float pa[8];
#pragma unroll
            for (int e = 0; e < 8; ++e) pa[e] = P_s[w][kt * 16 + 8 * hi + e][il];
            bf16x8 af = pack8(pa);
            bf16x8 v0 = *reinterpret_cast<const bf16x8*>(
                &v_bf_t[((size_t)(bh * 64 + il)) * NN + jt * 32 + kt * 16 + 8 * hi]);
            bf16x8 v1 = *reinterpret_cast<const bf16x8*>(
                &v_bf_t[((size_t)(bh * 64 + 32 + il)) * NN + jt * 32 + kt * 16 + 8 * hi]);
            O0 = MFMA32(af, v0, O0, 0, 0, 0);
            O1 = MFMA32(af, v1, O1, 0, 0, 0);
        }
        __syncthreads();
    }

    // write O (f32) to attn_out (B,N,H)
#pragma unroll
    for (int r = 0; r < 16; ++r) {
        int ir = (r & 3) + 8 * (r >> 2) + 4 * hi;
        size_t base = ((size_t)(b * NN + i0 + ir)) * HH + h * 64;
        attn_out[base + il] = O0[r];
        attn_out[base + 32 + il] = O1[r];
    }
}

// ---------------------------------------------------------------------------
// Kernel 4: O projection GEMM (8192x768)@(768x768) + bias + relu
// ---------------------------------------------------------------------------
__global__ __launch_bounds__(256) void k_ogemm(
        const float* __restrict__ A, const float* __restrict__ W,
        const float* __restrict__ bo, float* __restrict__ Cout) {
    __shared__ float As[16][65];
    __shared__ float Bs[16][65];
    int bm = blockIdx.x;
    int bn = blockIdx.y;
    int tid = threadIdx.x;
    int colBase = bn * 64;
    int ty = tid >> 4, tx = tid & 15;
    int rowBase = bm * 64;
    float acc[4][4] = {};
    for (int k0 = 0; k0 < HH; k0 += 16) {
#pragma unroll
        for (int l = 0; l < 4; ++l) {
            int e = tid + l * 256;
            int r = e >> 4, kk = e & 15;
            As[kk][r] = A[(size_t)(rowBase + r) * HH + k0 + kk];
        }
#pragma unroll
        for (int l = 0; l < 4; ++l) {
            int e = tid + l * 256;
            int kk = e >> 6, cc = e & 63;
            Bs[kk][cc] = W[(size_t)(k0 + kk) * HH + colBase + cc];
        }
        __syncthreads();
#pragma unroll
        for (int kk = 0; kk < 16; ++kk) {
            float a[4], bb[4];
#pragma unroll
            for (int i = 0; i < 4; ++i) a[i] = As[kk][ty * 4 + i];
#pragma unroll
            for (int j = 0; j < 4; ++j) bb[j] = Bs[kk][tx * 4 + j];
#pragma unroll
            for (int i = 0; i < 4; ++i)
#pragma unroll
                for (int j = 0; j < 4; ++j) acc[i][j] += a[i] * bb[j];
        }
        __syncthreads();
    }
#pragma unroll
    for (int i = 0; i < 4; ++i) {
        int row = rowBase + ty * 4 + i;
#pragma unroll
        for (int j = 0; j < 4; ++j) {
            int col = colBase + tx * 4 + j;
            float val = acc[i][j] + bo[col];
            Cout[(size_t)row * HH + col] = fmaxf(val, 0.f);
        }
    }
}

// ---------------------------------------------------------------------------
// Kernel 5: final LayerNorm(nodes + proj)
// ---------------------------------------------------------------------------
__global__ __launch_bounds__(256) void k_ln(
        const float* __restrict__ nodes, const float* __restrict__ proj,
        const float* __restrict__ g, const float* __restrict__ bta,
        float* __restrict__ out) {
    __shared__ float red[256];
    int row = blockIdx.x;
    int tid = threadIdx.x;
    float x[3];
    float s = 0.f;
#pragma unroll
    for (int l = 0; l < 3; ++l) {
        int c = tid + l * 256;
        x[l] = nodes[(size_t)row * HH + c] + proj[(size_t)row * HH + c];
        s += x[l];
    }
    red[tid] = s;
    __syncthreads();
    for (int st = 128; st > 0; st >>= 1) { if (tid < st) red[tid] += red[tid + st]; __syncthreads(); }
    float mean = red[0] / HH;
    __syncthreads();
    float vs = 0.f;
#pragma unroll
    for (int l = 0; l < 3; ++l) { float c = x[l] - mean; vs += c * c; }
    red[tid] = vs;
    __syncthreads();
    for (int st = 128; st > 0; st >>= 1) { if (tid < st) red[tid] += red[tid + st]; __syncthreads(); }
    float inv = rsqrtf(red[0] / HH + 1e-5f);
#pragma unroll
    for (int l = 0; l < 3; ++l) {
        int c = tid + l * 256;
        out[(size_t)row * HH + c] = (x[l] - mean) * inv * g[c] + bta[c];
    }
}

// ---------------------------------------------------------------------------
extern "C" void kernel_launch(void* const* d_in, const int* in_sizes, int n_in,
                              void* d_out, int out_size, void* d_ws, size_t ws_size,
                              hipStream_t stream) {
    const float* nodes     = (const float*)d_in[0];
    const float* bias      = (const float*)d_in[1];
    const float* pos_table = (const float*)d_in[3];
    const float* Wq = (const float*)d_in[4];  const float* bq = (const float*)d_in[5];
    const float* Wk = (const float*)d_in[6];  const float* bk = (const float*)d_in[7];
    const float* Wv = (const float*)d_in[8];  const float* bv = (const float*)d_in[9];
    const float* Wsk = (const float*)d_in[10]; const float* bsk = (const float*)d_in[11];
    const float* Wsv = (const float*)d_in[12]; const float* bsv = (const float*)d_in[13];
    const float* Wo = (const float*)d_in[14]; const float* bo = (const float*)d_in[15];
    const float* g_path = (const float*)d_in[16]; const float* b_path = (const float*)d_in[17];
    const float* g_norm = (const float*)d_in[18]; const float* b_norm = (const float*)d_in[19];

    float* out0 = (float*)d_out;                         // (B,N,H)
    float* wout = out0 + (size_t)BB * NN * HH;           // (B,HEADS,N,N)

    const size_t per = (size_t)BB * NHEADS * NN * DH;    // 6,291,456
    char* p = (char*)d_ws;
    unsigned short* q_bf   = (unsigned short*)p; p += per * 2;
    unsigned short* k_bf   = (unsigned short*)p; p += per * 2;
    unsigned short* v_bf_t = (unsigned short*)p; p += per * 2;
    unsigned short* skv_bf = (unsigned short*)p; p += 64 * 64 * 2;
    unsigned short* svv_t  = (unsigned short*)p; p += 64 * 48 * 2;
    float* ao_ws   = (float*)p; p += per * 4;
    float* proj_ws = (float*)p; p += per * 4;

    k_vocab<<<64, 128, 0, stream>>>(pos_table, g_path, b_path, Wsk, bsk, Wsv, bsv, skv_bf, svv_t);

    dim3 g2(128, 36);
    k_qkv<<<g2, 256, 0, stream>>>(nodes, Wq, bq, Wk, bk, Wv, bv, q_bf, k_bf, v_bf_t);

    k_attn<<<BB * NHEADS * 2, 256, 0, stream>>>(q_bf, k_bf, v_bf_t, skv_bf, svv_t, bias, wout, ao_ws);

    dim3 g4(128, 12);
    k_ogemm<<<g4, 256, 0, stream>>>(ao_ws, Wo, bo, proj_ws);

    k_ln<<<BB * NN, 256, 0, stream>>>(nodes, proj_ws, g_norm, b_norm, out0);
}

// Round 3
// 224.047 us; speedup vs baseline: 20.4391x; 3.9832x over previous
//
#include <hip/hip_runtime.h>
#include <hip/hip_bf16.h>

#define BB 32
#define NN 256
#define HH 768
#define NHEADS 12
#define DH 64
#define PHDIM 128
#define NVOCAB 35

typedef short bf16x8 __attribute__((ext_vector_type(8)));
typedef float f32x16 __attribute__((ext_vector_type(16)));

#define MFMA32 __builtin_amdgcn_mfma_f32_32x32x16_bf16

// round-to-nearest-even f32 -> bf16 bits
__device__ __forceinline__ unsigned short f2bf(float f) {
    unsigned u = __float_as_uint(f);
    unsigned r = (u + 0x7fffu + ((u >> 16) & 1u)) >> 16;
    return (unsigned short)r;
}

__device__ __forceinline__ bf16x8 pack8(const float f[8]) {
    bf16x8 r;
#pragma unroll
    for (int e = 0; e < 8; ++e) r[e] = (short)f2bf(f[e]);
    return r;
}

// ---------------------------------------------------------------------------
// Kernel 0a: cast nodes f32 -> bf16 (row-major [8192][768])
// ---------------------------------------------------------------------------
__global__ __launch_bounds__(256) void k_cast(const float* __restrict__ in,
                                              unsigned short* __restrict__ out) {
    int i = (blockIdx.x * 256 + threadIdx.x) * 4;
    float4 v = *reinterpret_cast<const float4*>(&in[i]);
    ushort4 o;
    o.x = f2bf(v.x); o.y = f2bf(v.y); o.z = f2bf(v.z); o.w = f2bf(v.w);
    *reinterpret_cast<ushort4*>(&out[i]) = o;
}

// ---------------------------------------------------------------------------
// Kernel 0b: transpose+cast weights -> Wt[z][col][k] bf16 (z: Wq,Wk,Wv,Wo)
// grid (12,12,4), 256 threads, 64x64 LDS tile
// ---------------------------------------------------------------------------
__global__ __launch_bounds__(256) void k_prep_w(
        const float* __restrict__ Wq, const float* __restrict__ Wk,
        const float* __restrict__ Wv, const float* __restrict__ Wo,
        unsigned short* __restrict__ Wt) {
    __shared__ unsigned short tile[64][72];   // row stride 144B (16B-aligned)
    int z = blockIdx.z;
    const float* W = (z == 0) ? Wq : (z == 1) ? Wk : (z == 2) ? Wv : Wo;
    unsigned short* out = Wt + (size_t)z * HH * HH;
    int k0 = blockIdx.x * 64, c0 = blockIdx.y * 64;
    int tid = threadIdx.x;
#pragma unroll
    for (int l = 0; l < 16; ++l) {
        int e = tid + l * 256;
        int r = e >> 6, c = e & 63;
        tile[c][r] = f2bf(W[(size_t)(k0 + r) * HH + c0 + c]);
    }
    __syncthreads();
#pragma unroll
    for (int l = 0; l < 2; ++l) {
        int e = tid + l * 256;
        int c = e >> 3, ch = e & 7;
        *reinterpret_cast<bf16x8*>(&out[(size_t)(c0 + c) * HH + k0 + ch * 8]) =
            *reinterpret_cast<const bf16x8*>(&tile[c][ch * 8]);
    }
}

// ---------------------------------------------------------------------------
// Kernel 1: LN(pos_table) @ Wsk/Wsv -> bf16 vocab tables
// ---------------------------------------------------------------------------
__global__ void k_vocab(const float* __restrict__ pos_table,
                        const float* __restrict__ g_path, const float* __restrict__ b_path,
                        const float* __restrict__ Wsk, const float* __restrict__ bsk,
                        const float* __restrict__ Wsv, const float* __restrict__ bsv,
                        unsigned short* __restrict__ skv_bf, unsigned short* __restrict__ svv_t_bf) {
    int v = blockIdx.x;
    int t = threadIdx.x;  // 128
    if (v >= NVOCAB) {
        if (t < 64) skv_bf[v * 64 + t] = 0;
        else if (v < 48) svv_t_bf[(t - 64) * 48 + v] = 0;
        return;
    }
    __shared__ float x[PHDIM];
    __shared__ float red[PHDIM];
    float xv = pos_table[v * PHDIM + t];
    red[t] = xv;
    __syncthreads();
    for (int s = 64; s > 0; s >>= 1) { if (t < s) red[t] += red[t + s]; __syncthreads(); }
    float mean = red[0] / PHDIM;
    __syncthreads();
    float c = xv - mean;
    red[t] = c * c;
    __syncthreads();
    for (int s = 64; s > 0; s >>= 1) { if (t < s) red[t] += red[t + s]; __syncthreads(); }
    float var = red[0] / PHDIM;
    float ln = (xv - mean) * rsqrtf(var + 1e-5f) * g_path[t] + b_path[t];
    __syncthreads();
    x[t] = ln;
    __syncthreads();
    if (t < 64) {
        float acc = bsk[t];
        for (int p = 0; p < PHDIM; ++p) acc += x[p] * Wsk[p * DH + t];
        skv_bf[v * 64 + t] = f2bf(acc);
    } else {
        int d = t - 64;
        float acc = bsv[d];
        for (int p = 0; p < PHDIM; ++p) acc += x[p] * Wsv[p * DH + d];
        svv_t_bf[d * 48 + v] = f2bf(acc);
    }
}

// ---------------------------------------------------------------------------
// Kernel 2: QKV MFMA GEMM (8192x768)bf16 @ Wt(2304x768 row=col,k) -> bf16 q/k/v
// 128x128 tile, BK=32, 4 waves 2x2, dbuf LDS via global_load_lds + XOR swizzle.
// Epilogue: q/k -> [bh][n][64] (q*0.125), v -> LDS transpose -> [bh][d][n].
// ---------------------------------------------------------------------------
__global__ __launch_bounds__(256) void k_qkv(
        const unsigned short* __restrict__ Abf, const unsigned short* __restrict__ Wt,
        const float* __restrict__ bq, const float* __restrict__ bk, const float* __restrict__ bv,
        unsigned short* __restrict__ q_bf, unsigned short* __restrict__ k_bf,
        unsigned short* __restrict__ v_bf_t) {
    __shared__ unsigned short Al[2][128 * 32];
    __shared__ unsigned short Bl[2][128 * 32];
    __shared__ unsigned short vstage[128][136];   // row stride 272B (16B-aligned)

    const int tid = threadIdx.x;
    const int w = tid >> 6, lane = tid & 63;
    const int il = lane & 31, hi = lane >> 5;
    const int wr = w >> 1, wc = w & 1;
    const int rowBase = blockIdx.x * 128;
    const int colBase = blockIdx.y * 128;
    const int sel = colBase / HH;
    const int jjBase0 = colBase - sel * HH;
    const float* bias = (sel == 0) ? bq : (sel == 1) ? bk : bv;

    f32x16 acc[2][2] = {};

    auto STAGE = [&](int buf, int k0) {
#pragma unroll
        for (int c = 0; c < 2; ++c) {
            int e = tid + c * 256;
            int row = e >> 2;
            int cb = (e & 3) << 4;
            int sc = cb ^ (((row >> 1) & 3) << 4);
            __builtin_amdgcn_global_load_lds(
                (const __attribute__((address_space(1))) unsigned int*)(Abf + (size_t)(rowBase + row) * HH + k0 + (sc >> 1)),
                (__attribute__((address_space(3))) unsigned int*)(&Al[buf][row * 32 + (cb >> 1)]), 16, 0, 0);
            __builtin_amdgcn_global_load_lds(
                (const __attribute__((address_space(1))) unsigned int*)(Wt + (size_t)(colBase + row) * HH + k0 + (sc >> 1)),
                (__attribute__((address_space(3))) unsigned int*)(&Bl[buf][row * 32 + (cb >> 1)]), 16, 0, 0);
        }
    };

    STAGE(0, 0);
    __syncthreads();
    for (int t = 0; t < 24; ++t) {
        int buf = t & 1;
        if (t < 23) STAGE(buf ^ 1, (t + 1) * 32);
#pragma unroll
        for (int ks = 0; ks < 2; ++ks) {
            bf16x8 af[2], bfr[2];
            int cb = (ks << 5) + (hi << 4);
#pragma unroll
            for (int t2 = 0; t2 < 2; ++t2) {
                int rrow = wr * 64 + t2 * 32 + il;
                af[t2] = *reinterpret_cast<const bf16x8*>(
                    &Al[buf][rrow * 32 + ((cb ^ (((rrow >> 1) & 3) << 4)) >> 1)]);
                int crow = wc * 64 + t2 * 32 + il;
                bfr[t2] = *reinterpret_cast<const bf16x8*>(
                    &Bl[buf][crow * 32 + ((cb ^ (((crow >> 1) & 3) << 4)) >> 1)]);
            }
            acc[0][0] = MFMA32(af[0], bfr[0], acc[0][0], 0, 0, 0);
            acc[0][1] = MFMA32(af[0], bfr[1], acc[0][1], 0, 0, 0);
            acc[1][0] = MFMA32(af[1], bfr[0], acc[1][0], 0, 0, 0);
            acc[1][1] = MFMA32(af[1], bfr[1], acc[1][1], 0, 0, 0);
        }
        __syncthreads();
    }

    if (sel < 2) {
        unsigned short* outp = (sel == 0) ? q_bf : k_bf;
        float scale = (sel == 0) ? 0.125f : 1.0f;
#pragma unroll
        for (int rt = 0; rt < 2; ++rt)
#pragma unroll
            for (int ct = 0; ct < 2; ++ct) {
                int jjB = jjBase0 + wc * 64 + ct * 32;
                int h = jjB >> 6, d = (jjB & 63) + il;
                float bias_v = bias[jjB + il];
#pragma unroll
                for (int r = 0; r < 16; ++r) {
                    int row = rowBase + wr * 64 + rt * 32 + ((r & 3) + 8 * (r >> 2) + 4 * hi);
                    int b = row >> 8, n = row & 255;
                    outp[((size_t)(b * NHEADS + h) * NN + n) * DH + d] =
                        f2bf((acc[rt][ct][r] + bias_v) * scale);
                }
            }
    } else {
#pragma unroll
        for (int rt = 0; rt < 2; ++rt)
#pragma unroll
            for (int ct = 0; ct < 2; ++ct) {
                int jjB = jjBase0 + wc * 64 + ct * 32;
                float bias_v = bias[jjB + il];
#pragma unroll
                for (int r = 0; r < 16; ++r) {
                    int rl = wr * 64 + rt * 32 + ((r & 3) + 8 * (r >> 2) + 4 * hi);
                    vstage[wc * 64 + ct * 32 + il][rl] = f2bf(acc[rt][ct][r] + bias_v);
                }
            }
        __syncthreads();
        int b = rowBase >> 8, n0 = rowBase & 255;
        int h0 = jjBase0 >> 6;
#pragma unroll
        for (int l = 0; l < 8; ++l) {
            int e = tid + l * 256;
            int cl = e >> 4;            // local col 0..127
            int nch = e & 15;           // 16B chunk
            size_t orow = (size_t)(b * NHEADS + h0 + (cl >> 6)) * DH + (cl & 63);
            *reinterpret_cast<bf16x8*>(&v_bf_t[orow * NN + n0 + nch * 8]) =
                *reinterpret_cast<const bf16x8*>(&vstage[cl][nch * 8]);
        }
    }
}

// ---------------------------------------------------------------------------
// Kernel 3: MFMA attention (unchanged math; writes bf16 attn_out)
// ---------------------------------------------------------------------------
__global__ __launch_bounds__(256, 2) void k_attn(
        const unsigned short* __restrict__ q_bf, const unsigned short* __restrict__ k_bf,
        const unsigned short* __restrict__ v_bf_t,
        const unsigned short* __restrict__ skv_bf, const unsigned short* __restrict__ svv_t_bf,
        const float* __restrict__ bias,
        float* __restrict__ wout, unsigned short* __restrict__ attn_out) {
    __shared__ float qs_ws[4][32][52];
    __shared__ float P_s[4][32][33];
    __shared__ float bias_s[NN];

    const int bx = blockIdx.x;
    const int bh = bx >> 1, half = bx & 1;
    const int b = bh / NHEADS, h = bh - b * NHEADS;
    const int tid = threadIdx.x;
    const int w = tid >> 6, lane = tid & 63;
    const int il = lane & 31, hi = lane >> 5;
    const int i0 = half * 128 + w * 32;
    const int ig = i0 + il;

    bias_s[tid] = bias[b * NN + tid];

    bf16x8 qf[4];
#pragma unroll
    for (int kt = 0; kt < 4; ++kt)
        qf[kt] = *reinterpret_cast<const bf16x8*>(
            &q_bf[((size_t)(bh * NN + ig)) * 64 + kt * 16 + 8 * hi]);

    {
        f32x16 qa0 = {}, qa1 = {};
#pragma unroll
        for (int kt = 0; kt < 4; ++kt) {
            bf16x8 s0 = *reinterpret_cast<const bf16x8*>(&skv_bf[(size_t)il * 64 + kt * 16 + 8 * hi]);
            bf16x8 s1 = *reinterpret_cast<const bf16x8*>(&skv_bf[(size_t)(32 + il) * 64 + kt * 16 + 8 * hi]);
            qa0 = MFMA32(qf[kt], s0, qa0, 0, 0, 0);
            qa1 = MFMA32(qf[kt], s1, qa1, 0, 0, 0);
        }
#pragma unroll
        for (int r = 0; r < 16; ++r) {
            int ir = (r & 3) + 8 * (r >> 2) + 4 * hi;
            qs_ws[w][ir][il] = qa0[r];
            if (il < 3) qs_ws[w][ir][32 + il] = qa1[r];
        }
    }
    __syncthreads();

    f32x16 S[8] = {};
#pragma unroll
    for (int jt = 0; jt < 8; ++jt) {
#pragma unroll
        for (int kt = 0; kt < 4; ++kt) {
            bf16x8 kf = *reinterpret_cast<const bf16x8*>(
                &k_bf[((size_t)(bh * NN + jt * 32 + il)) * 64 + kt * 16 + 8 * hi]);
            S[jt] = MFMA32(kf, qf[kt], S[jt], 0, 0, 0);
        }
    }

    {
        float qlo = qs_ws[w][il][0], qhi = qs_ws[w][il][34];
#pragma unroll
        for (int jt = 0; jt < 8; ++jt) {
#pragma unroll
            for (int rg = 0; rg < 4; ++rg) {
                int j0 = jt * 32 + rg * 8 + 4 * hi;
                float4 bv4 = *reinterpret_cast<const float4*>(&bias_s[j0]);
                float bvf[4] = {bv4.x, bv4.y, bv4.z, bv4.w};
#pragma unroll
                for (int e = 0; e < 4; ++e) {
                    int dd = j0 + e - ig;
                    float sw = (dd < -16) ? qlo : (dd > 16) ? qhi : qs_ws[w][il][dd + 17];
                    S[jt][rg * 4 + e] += bvf[e] + sw;
                }
            }
        }
    }

    float m = -3.4e38f;
#pragma unroll
    for (int jt = 0; jt < 8; ++jt)
#pragma unroll
        for (int r = 0; r < 16; ++r) m = fmaxf(m, S[jt][r]);
    m = fmaxf(m, __shfl_xor(m, 32));
    float sum = 0.f;
#pragma unroll
    for (int jt = 0; jt < 8; ++jt)
#pragma unroll
        for (int r = 0; r < 16; ++r) { float p = __expf(S[jt][r] - m); S[jt][r] = p; sum += p; }
    sum += __shfl_xor(sum, 32);
    float inv = 1.0f / sum;
#pragma unroll
    for (int jt = 0; jt < 8; ++jt)
#pragma unroll
        for (int r = 0; r < 16; ++r) S[jt][r] *= inv;

#pragma unroll
    for (int c = 0; c < 26; ++c) qs_ws[w][il][hi * 26 + c] = 0.f;
    {
        float elo = 0.f, ehi = 0.f;
#pragma unroll
        for (int jt = 0; jt < 8; ++jt)
#pragma unroll
            for (int r = 0; r < 16; ++r) {
                int j = jt * 32 + (r & 3) + 8 * (r >> 2) + 4 * hi;
                int dd = j - ig;
                float p = S[jt][r];
                if (dd < -16) elo += p;
                else if (dd > 16) ehi += p;
                else qs_ws[w][il][dd + 17] = p;
            }
        atomicAdd(&qs_ws[w][il][0], elo);
        atomicAdd(&qs_ws[w][il][34], ehi);
    }
    __syncthreads();

    f32x16 O0 = {}, O1 = {};
#pragma unroll
    for (int kt = 0; kt < 3; ++kt) {
        float a[8];
        float4 a0 = *reinterpret_cast<const float4*>(&qs_ws[w][il][kt * 16 + 8 * hi]);
        float4 a1 = *reinterpret_cast<const float4*>(&qs_ws[w][il][kt * 16 + 8 * hi + 4]);
        a[0] = a0.x; a[1] = a0.y; a[2] = a0.z; a[3] = a0.w;
        a[4] = a1.x; a[5] = a1.y; a[6] = a1.z; a[7] = a1.w;
        bf16x8 af = pack8(a);
        bf16x8 b0 = *reinterpret_cast<const bf16x8*>(&svv_t_bf[(size_t)il * 48 + kt * 16 + 8 * hi]);
        bf16x8 b1 = *reinterpret_cast<const bf16x8*>(&svv_t_bf[(size_t)(32 + il) * 48 + kt * 16 + 8 * hi]);
        O0 = MFMA32(af, b0, O0, 0, 0, 0);
        O1 = MFMA32(af, b1, O1, 0, 0, 0);
    }

#pragma unroll
    for (int jt = 0; jt < 8; ++jt) {
#pragma unroll
        for (int r = 0; r < 16; ++r) {
            int joff = (r & 3) + 8 * (r >> 2) + 4 * hi;
            P_s[w][joff][il] = S[jt][r];
        }
        __syncthreads();
#pragma unroll
        for (int rr = 0; rr < 16; ++rr) {
            int row = rr * 2 + hi;
            wout[((size_t)(bh * NN + i0 + row)) * NN + jt * 32 + il] = P_s[w][il][row];
        }
#pragma unroll
        for (int kt = 0; kt < 2; ++kt) {
            float pa[8];
#pragma unroll
            for (int e = 0; e < 8; ++e) pa[e] = P_s[w][kt * 16 + 8 * hi + e][il];
            bf16x8 af = pack8(pa);
            bf16x8 v0 = *reinterpret_cast<const bf16x8*>(
                &v_bf_t[((size_t)(bh * 64 + il)) * NN + jt * 32 + kt * 16 + 8 * hi]);
            bf16x8 v1 = *reinterpret_cast<const bf16x8*>(
                &v_bf_t[((size_t)(bh * 64 + 32 + il)) * NN + jt * 32 + kt * 16 + 8 * hi]);
            O0 = MFMA32(af, v0, O0, 0, 0, 0);
            O1 = MFMA32(af, v1, O1, 0, 0, 0);
        }
        __syncthreads();
    }

#pragma unroll
    for (int r = 0; r < 16; ++r) {
        int ir = (r & 3) + 8 * (r >> 2) + 4 * hi;
        size_t base = ((size_t)(b * NN + i0 + ir)) * HH + h * 64;
        attn_out[base + il] = f2bf(O0[r]);
        attn_out[base + 32 + il] = f2bf(O1[r]);
    }
}

// ---------------------------------------------------------------------------
// Kernel 4: O-projection MFMA GEMM (8192x768)bf16 @ Wo_t + bias + relu -> f32
// ---------------------------------------------------------------------------
__global__ __launch_bounds__(256) void k_ogemm(
        const unsigned short* __restrict__ Abf, const unsigned short* __restrict__ Bt,
        const float* __restrict__ bo, float* __restrict__ Cout) {
    __shared__ unsigned short Al[2][128 * 32];
    __shared__ unsigned short Bl[2][128 * 32];

    const int tid = threadIdx.x;
    const int w = tid >> 6, lane = tid & 63;
    const int il = lane & 31, hi = lane >> 5;
    const int wr = w >> 1, wc = w & 1;
    const int rowBase = blockIdx.x * 128;
    const int colBase = blockIdx.y * 128;

    f32x16 acc[2][2] = {};

    auto STAGE = [&](int buf, int k0) {
#pragma unroll
        for (int c = 0; c < 2; ++c) {
            int e = tid + c * 256;
            int row = e >> 2;
            int cb = (e & 3) << 4;
            int sc = cb ^ (((row >> 1) & 3) << 4);
            __builtin_amdgcn_global_load_lds(
                (const __attribute__((address_space(1))) unsigned int*)(Abf + (size_t)(rowBase + row) * HH + k0 + (sc >> 1)),
                (__attribute__((address_space(3))) unsigned int*)(&Al[buf][row * 32 + (cb >> 1)]), 16, 0, 0);
            __builtin_amdgcn_global_load_lds(
                (const __attribute__((address_space(1))) unsigned int*)(Bt + (size_t)(colBase + row) * HH + k0 + (sc >> 1)),
                (__attribute__((address_space(3))) unsigned int*)(&Bl[buf][row * 32 + (cb >> 1)]), 16, 0, 0);
        }
    };

    STAGE(0, 0);
    __syncthreads();
    for (int t = 0; t < 24; ++t) {
        int buf = t & 1;
        if (t < 23) STAGE(buf ^ 1, (t + 1) * 32);
#pragma unroll
        for (int ks = 0; ks < 2; ++ks) {
            bf16x8 af[2], bfr[2];
            int cb = (ks << 5) + (hi << 4);
#pragma unroll
            for (int t2 = 0; t2 < 2; ++t2) {
                int rrow = wr * 64 + t2 * 32 + il;
                af[t2] = *reinterpret_cast<const bf16x8*>(
                    &Al[buf][rrow * 32 + ((cb ^ (((rrow >> 1) & 3) << 4)) >> 1)]);
                int crow = wc * 64 + t2 * 32 + il;
                bfr[t2] = *reinterpret_cast<const bf16x8*>(
                    &Bl[buf][crow * 32 + ((cb ^ (((crow >> 1) & 3) << 4)) >> 1)]);
            }
            acc[0][0] = MFMA32(af[0], bfr[0], acc[0][0], 0, 0, 0);
            acc[0][1] = MFMA32(af[0], bfr[1], acc[0][1], 0, 0, 0);
            acc[1][0] = MFMA32(af[1], bfr[0], acc[1][0], 0, 0, 0);
            acc[1][1] = MFMA32(af[1], bfr[1], acc[1][1], 0, 0, 0);
        }
        __syncthreads();
    }

#pragma unroll
    for (int rt = 0; rt < 2; ++rt)
#pragma unroll
        for (int ct = 0; ct < 2; ++ct) {
            int col = colBase + wc * 64 + ct * 32 + il;
            float bias_v = bo[col];
#pragma unroll
            for (int r = 0; r < 16; ++r) {
                int row = rowBase + wr * 64 + rt * 32 + ((r & 3) + 8 * (r >> 2) + 4 * hi);
                Cout[(size_t)row * HH + col] = fmaxf(acc[rt][ct][r] + bias_v, 0.f);
            }
        }
}

// ---------------------------------------------------------------------------
// Kernel 5: final LayerNorm(nodes + proj), single-pass (sum, sumsq) + shfl
// ---------------------------------------------------------------------------
__global__ __launch_bounds__(256) void k_ln(
        const float* __restrict__ nodes, const float* __restrict__ proj,
        const float* __restrict__ g, const float* __restrict__ bta,
        float* __restrict__ out) {
    __shared__ float red[2][4];
    int row = blockIdx.x;
    int tid = threadIdx.x;
    int w = tid >> 6, lane = tid & 63;
    float x[3];
    float s = 0.f, s2 = 0.f;
#pragma unroll
    for (int l = 0; l < 3; ++l) {
        int c = tid + l * 256;
        x[l] = nodes[(size_t)row * HH + c] + proj[(size_t)row * HH + c];
        s += x[l];
        s2 += x[l] * x[l];
    }
#pragma unroll
    for (int off = 32; off > 0; off >>= 1) {
        s += __shfl_xor(s, off);
        s2 += __shfl_xor(s2, off);
    }
    if (lane == 0) { red[0][w] = s; red[1][w] = s2; }
    __syncthreads();
    float ts = red[0][0] + red[0][1] + red[0][2] + red[0][3];
    float ts2 = red[1][0] + red[1][1] + red[1][2] + red[1][3];
    float mean = ts / HH;
    float var = ts2 / HH - mean * mean;
    float inv = rsqrtf(fmaxf(var, 0.f) + 1e-5f);
#pragma unroll
    for (int l = 0; l < 3; ++l) {
        int c = tid + l * 256;
        out[(size_t)row * HH + c] = (x[l] - mean) * inv * g[c] + bta[c];
    }
}

// ---------------------------------------------------------------------------
extern "C" void kernel_launch(void* const* d_in, const int* in_sizes, int n_in,
                              void* d_out, int out_size, void* d_ws, size_t ws_size,
                              hipStream_t stream) {
    const float* nodes     = (const float*)d_in[0];
    const float* bias      = (const float*)d_in[1];
    const float* pos_table = (const float*)d_in[3];
    const float* Wq = (const float*)d_in[4];  const float* bq = (const float*)d_in[5];
    const float* Wk = (const float*)d_in[6];  const float* bk = (const float*)d_in[7];
    const float* Wv = (const float*)d_in[8];  const float* bv = (const float*)d_in[9];
    const float* Wsk = (const float*)d_in[10]; const float* bsk = (const float*)d_in[11];
    const float* Wsv = (const float*)d_in[12]; const float* bsv = (const float*)d_in[13];
    const float* Wo = (const float*)d_in[14]; const float* bo = (const float*)d_in[15];
    const float* g_path = (const float*)d_in[16]; const float* b_path = (const float*)d_in[17];
    const float* g_norm = (const float*)d_in[18]; const float* b_norm = (const float*)d_in[19];

    float* out0 = (float*)d_out;                         // (B,N,H)
    float* wout = out0 + (size_t)BB * NN * HH;           // (B,HEADS,N,N)

    const size_t per = (size_t)BB * NHEADS * NN * DH;    // 6,291,456 elements
    char* p = (char*)d_ws;
    unsigned short* q_bf    = (unsigned short*)p; p += per * 2;
    unsigned short* k_bf    = (unsigned short*)p; p += per * 2;
    unsigned short* v_bf_t  = (unsigned short*)p; p += per * 2;
    unsigned short* skv_bf  = (unsigned short*)p; p += 64 * 64 * 2;
    unsigned short* svv_t   = (unsigned short*)p; p += 64 * 48 * 2;
    unsigned short* nodes_bf= (unsigned short*)p; p += per * 2;
    unsigned short* Wt      = (unsigned short*)p; p += (size_t)4 * HH * HH * 2;
    unsigned short* attn_bf = (unsigned short*)p; p += per * 2;
    float* proj_ws = (float*)q_bf;   // aliases q_bf+k_bf (dead after k_attn)

    k_cast<<<per / 4 / 256, 256, 0, stream>>>(nodes, nodes_bf);

    dim3 gw(12, 12, 4);
    k_prep_w<<<gw, 256, 0, stream>>>(Wq, Wk, Wv, Wo, Wt);

    k_vocab<<<64, 128, 0, stream>>>(pos_table, g_path, b_path, Wsk, bsk, Wsv, bsv, skv_bf, svv_t);

    dim3 g2(64, 18);
    k_qkv<<<g2, 256, 0, stream>>>(nodes_bf, Wt, bq, bk, bv, q_bf, k_bf, v_bf_t);

    k_attn<<<BB * NHEADS * 2, 256, 0, stream>>>(q_bf, k_bf, v_bf_t, skv_bf, svv_t, bias, wout, attn_bf);

    dim3 g4(64, 6);
    k_ogemm<<<g4, 256, 0, stream>>>(attn_bf, Wt + (size_t)3 * HH * HH, bo, proj_ws);

    k_ln<<<BB * NN, 256, 0, stream>>>(nodes, proj_ws, g_norm, b_norm, out0);
}

// Round 4
// 221.378 us; speedup vs baseline: 20.6856x; 1.0121x over previous
//
#include <hip/hip_runtime.h>
#include <hip/hip_bf16.h>

#define BB 32
#define NN 256
#define HH 768
#define NHEADS 12
#define DH 64
#define PHDIM 128
#define NVOCAB 35

typedef short bf16x8 __attribute__((ext_vector_type(8)));
typedef float f32x16 __attribute__((ext_vector_type(16)));

#define MFMA32 __builtin_amdgcn_mfma_f32_32x32x16_bf16

// round-to-nearest-even f32 -> bf16 bits
__device__ __forceinline__ unsigned short f2bf(float f) {
    unsigned u = __float_as_uint(f);
    unsigned r = (u + 0x7fffu + ((u >> 16) & 1u)) >> 16;
    return (unsigned short)r;
}

__device__ __forceinline__ unsigned pk2(float a, float b) {
    return (unsigned)f2bf(a) | ((unsigned)f2bf(b) << 16);
}

__device__ __forceinline__ bf16x8 pack8(const float f[8]) {
    bf16x8 r;
#pragma unroll
    for (int e = 0; e < 8; ++e) r[e] = (short)f2bf(f[e]);
    return r;
}

// ---------------------------------------------------------------------------
// Kernel 0a: cast nodes f32 -> bf16
// ---------------------------------------------------------------------------
__global__ __launch_bounds__(256) void k_cast(const float* __restrict__ in,
                                              unsigned short* __restrict__ out) {
    int i = (blockIdx.x * 256 + threadIdx.x) * 4;
    float4 v = *reinterpret_cast<const float4*>(&in[i]);
    ushort4 o;
    o.x = f2bf(v.x); o.y = f2bf(v.y); o.z = f2bf(v.z); o.w = f2bf(v.w);
    *reinterpret_cast<ushort4*>(&out[i]) = o;
}

// ---------------------------------------------------------------------------
// Kernel 0b: transpose+cast weights -> Wt[z][col][k] bf16 (z: Wq,Wk,Wv,Wo)
// ---------------------------------------------------------------------------
__global__ __launch_bounds__(256) void k_prep_w(
        const float* __restrict__ Wq, const float* __restrict__ Wk,
        const float* __restrict__ Wv, const float* __restrict__ Wo,
        unsigned short* __restrict__ Wt) {
    __shared__ unsigned short tile[64][72];
    int z = blockIdx.z;
    const float* W = (z == 0) ? Wq : (z == 1) ? Wk : (z == 2) ? Wv : Wo;
    unsigned short* out = Wt + (size_t)z * HH * HH;
    int k0 = blockIdx.x * 64, c0 = blockIdx.y * 64;
    int tid = threadIdx.x;
#pragma unroll
    for (int l = 0; l < 16; ++l) {
        int e = tid + l * 256;
        int r = e >> 6, c = e & 63;
        tile[c][r] = f2bf(W[(size_t)(k0 + r) * HH + c0 + c]);
    }
    __syncthreads();
#pragma unroll
    for (int l = 0; l < 2; ++l) {
        int e = tid + l * 256;
        int c = e >> 3, ch = e & 7;
        *reinterpret_cast<bf16x8*>(&out[(size_t)(c0 + c) * HH + k0 + ch * 8]) =
            *reinterpret_cast<const bf16x8*>(&tile[c][ch * 8]);
    }
}

// ---------------------------------------------------------------------------
// Kernel 1: LN(pos_table) @ Wsk/Wsv -> bf16 vocab tables
// ---------------------------------------------------------------------------
__global__ void k_vocab(const float* __restrict__ pos_table,
                        const float* __restrict__ g_path, const float* __restrict__ b_path,
                        const float* __restrict__ Wsk, const float* __restrict__ bsk,
                        const float* __restrict__ Wsv, const float* __restrict__ bsv,
                        unsigned short* __restrict__ skv_bf, unsigned short* __restrict__ svv_t_bf) {
    int v = blockIdx.x;
    int t = threadIdx.x;  // 128
    if (v >= NVOCAB) {
        if (t < 64) skv_bf[v * 64 + t] = 0;
        else if (v < 48) svv_t_bf[(t - 64) * 48 + v] = 0;
        return;
    }
    __shared__ float x[PHDIM];
    __shared__ float red[PHDIM];
    float xv = pos_table[v * PHDIM + t];
    red[t] = xv;
    __syncthreads();
    for (int s = 64; s > 0; s >>= 1) { if (t < s) red[t] += red[t + s]; __syncthreads(); }
    float mean = red[0] / PHDIM;
    __syncthreads();
    float c = xv - mean;
    red[t] = c * c;
    __syncthreads();
    for (int s = 64; s > 0; s >>= 1) { if (t < s) red[t] += red[t + s]; __syncthreads(); }
    float var = red[0] / PHDIM;
    float ln = (xv - mean) * rsqrtf(var + 1e-5f) * g_path[t] + b_path[t];
    __syncthreads();
    x[t] = ln;
    __syncthreads();
    if (t < 64) {
        float acc = bsk[t];
        for (int p = 0; p < PHDIM; ++p) acc += x[p] * Wsk[p * DH + t];
        skv_bf[v * 64 + t] = f2bf(acc);
    } else {
        int d = t - 64;
        float acc = bsv[d];
        for (int p = 0; p < PHDIM; ++p) acc += x[p] * Wsv[p * DH + d];
        svv_t_bf[d * 48 + v] = f2bf(acc);
    }
}

// ---------------------------------------------------------------------------
// Kernel 2: QKV MFMA GEMM -> bf16 q/k ([bh][n][64]) and v^T ([bh][d][n])
// ---------------------------------------------------------------------------
__global__ __launch_bounds__(256) void k_qkv(
        const unsigned short* __restrict__ Abf, const unsigned short* __restrict__ Wt,
        const float* __restrict__ bq, const float* __restrict__ bk, const float* __restrict__ bv,
        unsigned short* __restrict__ q_bf, unsigned short* __restrict__ k_bf,
        unsigned short* __restrict__ v_bf_t) {
    __shared__ unsigned short Al[2][128 * 32];
    __shared__ unsigned short Bl[2][128 * 32];
    __shared__ unsigned short vstage[128][136];

    const int tid = threadIdx.x;
    const int w = tid >> 6, lane = tid & 63;
    const int il = lane & 31, hi = lane >> 5;
    const int wr = w >> 1, wc = w & 1;
    const int rowBase = blockIdx.x * 128;
    const int colBase = blockIdx.y * 128;
    const int sel = colBase / HH;
    const int jjBase0 = colBase - sel * HH;
    const float* bias = (sel == 0) ? bq : (sel == 1) ? bk : bv;

    f32x16 acc[2][2] = {};

    auto STAGE = [&](int buf, int k0) {
#pragma unroll
        for (int c = 0; c < 2; ++c) {
            int e = tid + c * 256;
            int row = e >> 2;
            int cb = (e & 3) << 4;
            int sc = cb ^ (((row >> 1) & 3) << 4);
            __builtin_amdgcn_global_load_lds(
                (const __attribute__((address_space(1))) unsigned int*)(Abf + (size_t)(rowBase + row) * HH + k0 + (sc >> 1)),
                (__attribute__((address_space(3))) unsigned int*)(&Al[buf][row * 32 + (cb >> 1)]), 16, 0, 0);
            __builtin_amdgcn_global_load_lds(
                (const __attribute__((address_space(1))) unsigned int*)(Wt + (size_t)(colBase + row) * HH + k0 + (sc >> 1)),
                (__attribute__((address_space(3))) unsigned int*)(&Bl[buf][row * 32 + (cb >> 1)]), 16, 0, 0);
        }
    };

    STAGE(0, 0);
    __syncthreads();
    for (int t = 0; t < 24; ++t) {
        int buf = t & 1;
        if (t < 23) STAGE(buf ^ 1, (t + 1) * 32);
#pragma unroll
        for (int ks = 0; ks < 2; ++ks) {
            bf16x8 af[2], bfr[2];
            int cb = (ks << 5) + (hi << 4);
#pragma unroll
            for (int t2 = 0; t2 < 2; ++t2) {
                int rrow = wr * 64 + t2 * 32 + il;
                af[t2] = *reinterpret_cast<const bf16x8*>(
                    &Al[buf][rrow * 32 + ((cb ^ (((rrow >> 1) & 3) << 4)) >> 1)]);
                int crow = wc * 64 + t2 * 32 + il;
                bfr[t2] = *reinterpret_cast<const bf16x8*>(
                    &Bl[buf][crow * 32 + ((cb ^ (((crow >> 1) & 3) << 4)) >> 1)]);
            }
            acc[0][0] = MFMA32(af[0], bfr[0], acc[0][0], 0, 0, 0);
            acc[0][1] = MFMA32(af[0], bfr[1], acc[0][1], 0, 0, 0);
            acc[1][0] = MFMA32(af[1], bfr[0], acc[1][0], 0, 0, 0);
            acc[1][1] = MFMA32(af[1], bfr[1], acc[1][1], 0, 0, 0);
        }
        __syncthreads();
    }

    if (sel < 2) {
        unsigned short* outp = (sel == 0) ? q_bf : k_bf;
        float scale = (sel == 0) ? 0.125f : 1.0f;
#pragma unroll
        for (int rt = 0; rt < 2; ++rt)
#pragma unroll
            for (int ct = 0; ct < 2; ++ct) {
                int jjB = jjBase0 + wc * 64 + ct * 32;
                int h = jjB >> 6, d = (jjB & 63) + il;
                float bias_v = bias[jjB + il];
#pragma unroll
                for (int r = 0; r < 16; ++r) {
                    int row = rowBase + wr * 64 + rt * 32 + ((r & 3) + 8 * (r >> 2) + 4 * hi);
                    int b = row >> 8, n = row & 255;
                    outp[((size_t)(b * NHEADS + h) * NN + n) * DH + d] =
                        f2bf((acc[rt][ct][r] + bias_v) * scale);
                }
            }
    } else {
#pragma unroll
        for (int rt = 0; rt < 2; ++rt)
#pragma unroll
            for (int ct = 0; ct < 2; ++ct) {
                int jjB = jjBase0 + wc * 64 + ct * 32;
                float bias_v = bias[jjB + il];
#pragma unroll
                for (int r = 0; r < 16; ++r) {
                    int rl = wr * 64 + rt * 32 + ((r & 3) + 8 * (r >> 2) + 4 * hi);
                    vstage[wc * 64 + ct * 32 + il][rl] = f2bf(acc[rt][ct][r] + bias_v);
                }
            }
        __syncthreads();
        int b = rowBase >> 8, n0 = rowBase & 255;
        int h0 = jjBase0 >> 6;
#pragma unroll
        for (int l = 0; l < 8; ++l) {
            int e = tid + l * 256;
            int cl = e >> 4;
            int nch = e & 15;
            size_t orow = (size_t)(b * NHEADS + h0 + (cl >> 6)) * DH + (cl & 63);
            *reinterpret_cast<bf16x8*>(&v_bf_t[orow * NN + n0 + nch * 8]) =
                *reinterpret_cast<const bf16x8*>(&vstage[cl][nch * 8]);
        }
    }
}

// ---------------------------------------------------------------------------
// Kernel 3: MFMA attention, barrier-free (per-wave LDS only; 1 barrier for bias).
// PV directly from S regs via bf16 pack + shfl_xor(32) B-fragments (O^T form).
// w staged as packed bf16 u32 pairs per 2-jt group -> float2 256B bursts.
// ---------------------------------------------------------------------------
__global__ __launch_bounds__(256, 2) void k_attn(
        const unsigned short* __restrict__ q_bf, const unsigned short* __restrict__ k_bf,
        const unsigned short* __restrict__ v_bf_t,
        const unsigned short* __restrict__ skv_bf, const unsigned short* __restrict__ svv_t_bf,
        const float* __restrict__ bias,
        float* __restrict__ wout, unsigned short* __restrict__ attn_out) {
    __shared__ float qs_ws[4][32][48];      // per-wave: qs then wsum
    __shared__ unsigned P2[4][32][33];      // per-wave: packed bf16 P pairs (2 jt tiles)
    __shared__ float bias_s[NN];

    const int bx0 = blockIdx.x;
    const int bx = (bx0 & 7) * 96 + (bx0 >> 3);   // XCD-chunked: (bh,0),(bh,1) same XCD
    const int bh = bx >> 1, half = bx & 1;
    const int b = bh / NHEADS, h = bh - b * NHEADS;
    const int tid = threadIdx.x;
    const int w = tid >> 6, lane = tid & 63;
    const int il = lane & 31, hi = lane >> 5;
    const int i0 = half * 128 + w * 32;
    const int ig = i0 + il;

    bias_s[tid] = bias[b * NN + tid];

    // Q fragments
    bf16x8 qf[4];
#pragma unroll
    for (int kt = 0; kt < 4; ++kt)
        qf[kt] = *reinterpret_cast<const bf16x8*>(
            &q_bf[((size_t)(bh * NN + ig)) * 64 + kt * 16 + 8 * hi]);

    // qs = Q @ skv^T  (i x vocab) -- per-wave LDS, no barrier needed
    {
        f32x16 qa0 = {}, qa1 = {};
#pragma unroll
        for (int kt = 0; kt < 4; ++kt) {
            bf16x8 s0 = *reinterpret_cast<const bf16x8*>(&skv_bf[(size_t)il * 64 + kt * 16 + 8 * hi]);
            bf16x8 s1 = *reinterpret_cast<const bf16x8*>(&skv_bf[(size_t)(32 + il) * 64 + kt * 16 + 8 * hi]);
            qa0 = MFMA32(qf[kt], s0, qa0, 0, 0, 0);
            qa1 = MFMA32(qf[kt], s1, qa1, 0, 0, 0);
        }
#pragma unroll
        for (int r = 0; r < 16; ++r) {
            int ir = (r & 3) + 8 * (r >> 2) + 4 * hi;
            qs_ws[w][ir][il] = qa0[r];
            if (il < 3) qs_ws[w][ir][32 + il] = qa1[r];
        }
    }

    // QK^T: S^T tiles (j x i)
    f32x16 S[8] = {};
#pragma unroll
    for (int jt = 0; jt < 8; ++jt) {
#pragma unroll
        for (int kt = 0; kt < 4; ++kt) {
            bf16x8 kf = *reinterpret_cast<const bf16x8*>(
                &k_bf[((size_t)(bh * NN + jt * 32 + il)) * 64 + kt * 16 + 8 * hi]);
            S[jt] = MFMA32(kf, qf[kt], S[jt], 0, 0, 0);
        }
    }

    __syncthreads();   // bias_s ready (only cross-wave dependency in the kernel)

    // add struct_w (clamped qs lookup) + bias
    {
        float qlo = qs_ws[w][il][0], qhi = qs_ws[w][il][34];
#pragma unroll
        for (int jt = 0; jt < 8; ++jt) {
#pragma unroll
            for (int rg = 0; rg < 4; ++rg) {
                int j0 = jt * 32 + rg * 8 + 4 * hi;
                float4 bv4 = *reinterpret_cast<const float4*>(&bias_s[j0]);
                float bvf[4] = {bv4.x, bv4.y, bv4.z, bv4.w};
#pragma unroll
                for (int e = 0; e < 4; ++e) {
                    int dd = j0 + e - ig;
                    float sw = (dd < -16) ? qlo : (dd > 16) ? qhi : qs_ws[w][il][dd + 17];
                    S[jt][rg * 4 + e] += bvf[e] + sw;
                }
            }
        }
    }

    // register softmax (row split between lane and lane^32)
    float m = -3.4e38f;
#pragma unroll
    for (int jt = 0; jt < 8; ++jt)
#pragma unroll
        for (int r = 0; r < 16; ++r) m = fmaxf(m, S[jt][r]);
    m = fmaxf(m, __shfl_xor(m, 32));
    float sum = 0.f;
#pragma unroll
    for (int jt = 0; jt < 8; ++jt)
#pragma unroll
        for (int r = 0; r < 16; ++r) { float p = __expf(S[jt][r] - m); S[jt][r] = p; sum += p; }
    sum += __shfl_xor(sum, 32);
    float inv = 1.0f / sum;
#pragma unroll
    for (int jt = 0; jt < 8; ++jt)
#pragma unroll
        for (int r = 0; r < 16; ++r) S[jt][r] *= inv;

    // wsum histogram into qs_ws (qs dead; per-wave, in-order DS)
#pragma unroll
    for (int c = 0; c < 24; ++c) qs_ws[w][il][hi * 24 + c] = 0.f;
    {
        float elo = 0.f, ehi = 0.f;
#pragma unroll
        for (int jt = 0; jt < 8; ++jt)
#pragma unroll
            for (int r = 0; r < 16; ++r) {
                int j = jt * 32 + (r & 3) + 8 * (r >> 2) + 4 * hi;
                int dd = j - ig;
                float p = S[jt][r];
                if (dd < -16) elo += p;
                else if (dd > 16) ehi += p;
                else qs_ws[w][il][dd + 17] = p;
            }
        atomicAdd(&qs_ws[w][il][0], elo);
        atomicAdd(&qs_ws[w][il][34], ehi);
    }

    // struct-PV (O^T): A = svv^T rows d, B = wsum^T from qs_ws
    f32x16 O0 = {}, O1 = {};
#pragma unroll
    for (int kt = 0; kt < 3; ++kt) {
        float4 a0 = *reinterpret_cast<const float4*>(&qs_ws[w][il][kt * 16 + 8 * hi]);
        float4 a1 = *reinterpret_cast<const float4*>(&qs_ws[w][il][kt * 16 + 8 * hi + 4]);
        float af[8] = {a0.x, a0.y, a0.z, a0.w, a1.x, a1.y, a1.z, a1.w};
        bf16x8 Bf = pack8(af);
        bf16x8 sa0 = *reinterpret_cast<const bf16x8*>(&svv_t_bf[(size_t)il * 48 + kt * 16 + 8 * hi]);
        bf16x8 sa1 = *reinterpret_cast<const bf16x8*>(&svv_t_bf[(size_t)(32 + il) * 48 + kt * 16 + 8 * hi]);
        O0 = MFMA32(sa0, Bf, O0, 0, 0, 0);
        O1 = MFMA32(sa1, Bf, O1, 0, 0, 0);
    }

    // main PV (O^T) from regs + w-write, per 2-jt group
    const unsigned short* vrow0 = &v_bf_t[((size_t)bh * 64 + il) * NN];
    const unsigned short* vrow1 = &v_bf_t[((size_t)bh * 64 + 32 + il) * NN];
#pragma unroll
    for (int jt2 = 0; jt2 < 4; ++jt2) {
#pragma unroll
        for (int p = 0; p < 2; ++p) {
            int jt = jt2 * 2 + p;
#pragma unroll
            for (int ks = 0; ks < 2; ++ks) {
                unsigned w0 = pk2(S[jt][8 * ks + 0], S[jt][8 * ks + 1]);
                unsigned w1 = pk2(S[jt][8 * ks + 2], S[jt][8 * ks + 3]);
                unsigned w2 = pk2(S[jt][8 * ks + 4], S[jt][8 * ks + 5]);
                unsigned w3 = pk2(S[jt][8 * ks + 6], S[jt][8 * ks + 7]);
                // stage packed pairs for the w-write (pair index = joff>>1)
                int pb = p * 16 + 8 * ks + 2 * hi;
                P2[w][pb + 0][il] = w0;
                P2[w][pb + 1][il] = w1;
                P2[w][pb + 4][il] = w2;
                P2[w][pb + 5][il] = w3;
                // B-fragment via half-exchange with lane^32
                unsigned s0 = hi ? w0 : w2, s1 = hi ? w1 : w3;
                unsigned y0 = (unsigned)__shfl_xor((int)s0, 32);
                unsigned y1 = (unsigned)__shfl_xor((int)s1, 32);
                union { bf16x8 v; unsigned u[4]; } Bf;
                Bf.u[0] = hi ? y0 : w0;
                Bf.u[1] = hi ? y1 : w1;
                Bf.u[2] = hi ? w2 : y0;
                Bf.u[3] = hi ? w3 : y1;
                bf16x8 va0 = *reinterpret_cast<const bf16x8*>(&vrow0[jt * 32 + ks * 16 + 8 * hi]);
                bf16x8 va1 = *reinterpret_cast<const bf16x8*>(&vrow1[jt * 32 + ks * 16 + 8 * hi]);
                O0 = MFMA32(va0, Bf.v, O0, 0, 0, 0);
                O1 = MFMA32(va1, Bf.v, O1, 0, 0, 0);
            }
        }
        // coalesced w rows: lane reads pair il of row -> float2 (256B/burst)
#pragma unroll
        for (int rr = 0; rr < 16; ++rr) {
            int row = rr * 2 + hi;
            unsigned u = P2[w][il][row];
            float2 val;
            val.x = __uint_as_float((u & 0xffffu) << 16);
            val.y = __uint_as_float(u & 0xffff0000u);
            *reinterpret_cast<float2*>(
                &wout[((size_t)(bh * NN + i0 + row)) * NN + jt2 * 64 + 2 * il]) = val;
        }
    }

    // attn_out (bf16), O^T layout: lane owns row i=i0+il, regs span d
#pragma unroll
    for (int qq = 0; qq < 4; ++qq) {
        int d0 = 8 * qq + 4 * hi;
        ushort4 o0, o1;
        o0.x = f2bf(O0[4 * qq + 0]); o0.y = f2bf(O0[4 * qq + 1]);
        o0.z = f2bf(O0[4 * qq + 2]); o0.w = f2bf(O0[4 * qq + 3]);
        o1.x = f2bf(O1[4 * qq + 0]); o1.y = f2bf(O1[4 * qq + 1]);
        o1.z = f2bf(O1[4 * qq + 2]); o1.w = f2bf(O1[4 * qq + 3]);
        size_t base = ((size_t)(b * NN + i0 + il)) * HH + h * 64;
        *reinterpret_cast<ushort4*>(&attn_out[base + d0]) = o0;
        *reinterpret_cast<ushort4*>(&attn_out[base + 32 + d0]) = o1;
    }
}

// ---------------------------------------------------------------------------
// Kernel 4: O-projection MFMA GEMM + bias + relu -> f32
// ---------------------------------------------------------------------------
__global__ __launch_bounds__(256) void k_ogemm(
        const unsigned short* __restrict__ Abf, const unsigned short* __restrict__ Bt,
        const float* __restrict__ bo, float* __restrict__ Cout) {
    __shared__ unsigned short Al[2][128 * 32];
    __shared__ unsigned short Bl[2][128 * 32];

    const int tid = threadIdx.x;
    const int w = tid >> 6, lane = tid & 63;
    const int il = lane & 31, hi = lane >> 5;
    const int wr = w >> 1, wc = w & 1;
    const int rowBase = blockIdx.x * 128;
    const int colBase = blockIdx.y * 128;

    f32x16 acc[2][2] = {};

    auto STAGE = [&](int buf, int k0) {
#pragma unroll
        for (int c = 0; c < 2; ++c) {
            int e = tid + c * 256;
            int row = e >> 2;
            int cb = (e & 3) << 4;
            int sc = cb ^ (((row >> 1) & 3) << 4);
            __builtin_amdgcn_global_load_lds(
                (const __attribute__((address_space(1))) unsigned int*)(Abf + (size_t)(rowBase + row) * HH + k0 + (sc >> 1)),
                (__attribute__((address_space(3))) unsigned int*)(&Al[buf][row * 32 + (cb >> 1)]), 16, 0, 0);
            __builtin_amdgcn_global_load_lds(
                (const __attribute__((address_space(1))) unsigned int*)(Bt + (size_t)(colBase + row) * HH + k0 + (sc >> 1)),
                (__attribute__((address_space(3))) unsigned int*)(&Bl[buf][row * 32 + (cb >> 1)]), 16, 0, 0);
        }
    };

    STAGE(0, 0);
    __syncthreads();
    for (int t = 0; t < 24; ++t) {
        int buf = t & 1;
        if (t < 23) STAGE(buf ^ 1, (t + 1) * 32);
#pragma unroll
        for (int ks = 0; ks < 2; ++ks) {
            bf16x8 af[2], bfr[2];
            int cb = (ks << 5) + (hi << 4);
#pragma unroll
            for (int t2 = 0; t2 < 2; ++t2) {
                int rrow = wr * 64 + t2 * 32 + il;
                af[t2] = *reinterpret_cast<const bf16x8*>(
                    &Al[buf][rrow * 32 + ((cb ^ (((rrow >> 1) & 3) << 4)) >> 1)]);
                int crow = wc * 64 + t2 * 32 + il;
                bfr[t2] = *reinterpret_cast<const bf16x8*>(
                    &Bl[buf][crow * 32 + ((cb ^ (((crow >> 1) & 3) << 4)) >> 1)]);
            }
            acc[0][0] = MFMA32(af[0], bfr[0], acc[0][0], 0, 0, 0);
            acc[0][1] = MFMA32(af[0], bfr[1], acc[0][1], 0, 0, 0);
            acc[1][0] = MFMA32(af[1], bfr[0], acc[1][0], 0, 0, 0);
            acc[1][1] = MFMA32(af[1], bfr[1], acc[1][1], 0, 0, 0);
        }
        __syncthreads();
    }

#pragma unroll
    for (int rt = 0; rt < 2; ++rt)
#pragma unroll
        for (int ct = 0; ct < 2; ++ct) {
            int col = colBase + wc * 64 + ct * 32 + il;
            float bias_v = bo[col];
#pragma unroll
            for (int r = 0; r < 16; ++r) {
                int row = rowBase + wr * 64 + rt * 32 + ((r & 3) + 8 * (r >> 2) + 4 * hi);
                Cout[(size_t)row * HH + col] = fmaxf(acc[rt][ct][r] + bias_v, 0.f);
            }
        }
}

// ---------------------------------------------------------------------------
// Kernel 5: final LayerNorm(nodes + proj), single-pass + shfl
// ---------------------------------------------------------------------------
__global__ __launch_bounds__(256) void k_ln(
        const float* __restrict__ nodes, const float* __restrict__ proj,
        const float* __restrict__ g, const float* __restrict__ bta,
        float* __restrict__ out) {
    __shared__ float red[2][4];
    int row = blockIdx.x;
    int tid = threadIdx.x;
    int w = tid >> 6, lane = tid & 63;
    float x[3];
    float s = 0.f, s2 = 0.f;
#pragma unroll
    for (int l = 0; l < 3; ++l) {
        int c = tid + l * 256;
        x[l] = nodes[(size_t)row * HH + c] + proj[(size_t)row * HH + c];
        s += x[l];
        s2 += x[l] * x[l];
    }
#pragma unroll
    for (int off = 32; off > 0; off >>= 1) {
        s += __shfl_xor(s, off);
        s2 += __shfl_xor(s2, off);
    }
    if (lane == 0) { red[0][w] = s; red[1][w] = s2; }
    __syncthreads();
    float ts = red[0][0] + red[0][1] + red[0][2] + red[0][3];
    float ts2 = red[1][0] + red[1][1] + red[1][2] + red[1][3];
    float mean = ts / HH;
    float var = ts2 / HH - mean * mean;
    float inv = rsqrtf(fmaxf(var, 0.f) + 1e-5f);
#pragma unroll
    for (int l = 0; l < 3; ++l) {
        int c = tid + l * 256;
        out[(size_t)row * HH + c] = (x[l] - mean) * inv * g[c] + bta[c];
    }
}

// ---------------------------------------------------------------------------
extern "C" void kernel_launch(void* const* d_in, const int* in_sizes, int n_in,
                              void* d_out, int out_size, void* d_ws, size_t ws_size,
                              hipStream_t stream) {
    const float* nodes     = (const float*)d_in[0];
    const float* bias      = (const float*)d_in[1];
    const float* pos_table = (const float*)d_in[3];
    const float* Wq = (const float*)d_in[4];  const float* bq = (const float*)d_in[5];
    const float* Wk = (const float*)d_in[6];  const float* bk = (const float*)d_in[7];
    const float* Wv = (const float*)d_in[8];  const float* bv = (const float*)d_in[9];
    const float* Wsk = (const float*)d_in[10]; const float* bsk = (const float*)d_in[11];
    const float* Wsv = (const float*)d_in[12]; const float* bsv = (const float*)d_in[13];
    const float* Wo = (const float*)d_in[14]; const float* bo = (const float*)d_in[15];
    const float* g_path = (const float*)d_in[16]; const float* b_path = (const float*)d_in[17];
    const float* g_norm = (const float*)d_in[18]; const float* b_norm = (const float*)d_in[19];

    float* out0 = (float*)d_out;                         // (B,N,H)
    float* wout = out0 + (size_t)BB * NN * HH;           // (B,HEADS,N,N)

    const size_t per = (size_t)BB * NN * HH;             // 6,291,456 elements
    char* p = (char*)d_ws;
    unsigned short* q_bf    = (unsigned short*)p; p += per * 2;
    unsigned short* k_bf    = (unsigned short*)p; p += per * 2;
    unsigned short* v_bf_t  = (unsigned short*)p; p += per * 2;
    unsigned short* skv_bf  = (unsigned short*)p; p += 64 * 64 * 2;
    unsigned short* svv_t   = (unsigned short*)p; p += 64 * 48 * 2;
    unsigned short* nodes_bf= (unsigned short*)p; p += per * 2;
    unsigned short* Wt      = (unsigned short*)p; p += (size_t)4 * HH * HH * 2;
    unsigned short* attn_bf = (unsigned short*)p; p += per * 2;
    float* proj_ws = (float*)q_bf;   // aliases q_bf+k_bf (dead after k_attn)

    k_cast<<<per / 4 / 256, 256, 0, stream>>>(nodes, nodes_bf);

    dim3 gw(12, 12, 4);
    k_prep_w<<<gw, 256, 0, stream>>>(Wq, Wk, Wv, Wo, Wt);

    k_vocab<<<64, 128, 0, stream>>>(pos_table, g_path, b_path, Wsk, bsk, Wsv, bsv, skv_bf, svv_t);

    dim3 g2(64, 18);
    k_qkv<<<g2, 256, 0, stream>>>(nodes_bf, Wt, bq, bk, bv, q_bf, k_bf, v_bf_t);

    k_attn<<<BB * NHEADS * 2, 256, 0, stream>>>(q_bf, k_bf, v_bf_t, skv_bf, svv_t, bias, wout, attn_bf);

    dim3 g4(64, 6);
    k_ogemm<<<g4, 256, 0, stream>>>(attn_bf, Wt + (size_t)3 * HH * HH, bo, proj_ws);

    k_ln<<<BB * NN, 256, 0, stream>>>(nodes, proj_ws, g_norm, b_norm, out0);
}